// Round 6
// baseline (145.405 us; speedup 1.0000x reference)
//
#include <hip/hip_runtime.h>

// NGF loss: g = normalized gradient (central diff interior, one-sided at edges),
// loss = 1 - mean( (g0 . g1)^2 ).  B=64, C=1, H=512, W=512, fp32.
//
// R15 probe: the load-flavor x concurrency matrix has one untested cell.
// plain{8,16 waves/CU} = 45-52us (L1-allocate serializes, waves don't help);
// NT{8 waves/CU} = 40us (champion). NT pin arithmetic: 3.6TB/s / 256CU x 375ns
// = ~82 lines in flight/CU = ~10/wave — a per-wave vmcnt window, not clearly a
// per-CU pool. This probe: NT + 16 waves/CU (RPT=8, 4096 waves, 1024x256,
// launch_bounds(256,4); 40 VGPR -> residency not VGPR-limited; R11 measured
// 30-34% occupancy with this exact geometry). If per-wave windows scale:
// kernel -> 28-34us. If per-CU pool: ~45-47us (R11 repeat) -> restore R14 and
// declare roofline with the complete 2x2.

#define HH 512
#define WW 512
#define NGF_EPS 1e-10f
#define RPT 8    // rows walked per wave; 64 chunks per image

typedef float vf4 __attribute__((ext_vector_type(4)));

__device__ __forceinline__ float rcp_fast(float x) { return __builtin_amdgcn_rcpf(x); }
__device__ __forceinline__ vf4 ldnt(const float* p) {
    return __builtin_nontemporal_load((const vf4*)p);
}

// waves = 64 imgs * (512/RPT = 64 chunks) = 4096 -> 1024 blocks x 256 threads
// launch_bounds(256,4): 4 waves/EU -> 16 waves/CU resident.
__global__ __launch_bounds__(256, 4) void ngf_partial(const float* __restrict__ I0,
                                                      const float* __restrict__ I1,
                                                      float* __restrict__ partials) {
    const int tid  = threadIdx.x;
    const int wv   = tid >> 6;
    const int lane = tid & 63;
    const int gw   = blockIdx.x * 4 + wv;   // global wave id, 0..4095
    const int img  = gw >> 6;               // 0..63
    const int ck   = gw & 63;               // row-chunk 0..63
    const int h0   = ck * RPT;

    const float* p0 = I0 + (size_t)img * (HH * WW) + lane * 8;
    const float* p1 = I1 + (size_t)img * (HH * WW) + lane * 8;

    // 3-row window (u = h-1 clamped, c = h, n = h+1) + prefetch m = h+2.
    vf4 u0a, u0b, u1a, u1b, c0a, c0b, c1a, c1b, n0a, n0b, n1a, n1b;
    {
        const int ru = (h0 > 0) ? (h0 - 1) * WW : 0;
        const int rc = h0 * WW;
        const int rn = (h0 + 1) * WW;       // h0 <= 504 -> always valid
        u0a = ldnt(p0 + ru);     u0b = ldnt(p0 + ru + 4);
        u1a = ldnt(p1 + ru);     u1b = ldnt(p1 + ru + 4);
        c0a = ldnt(p0 + rc);     c0b = ldnt(p0 + rc + 4);
        c1a = ldnt(p1 + rc);     c1b = ldnt(p1 + rc + 4);
        n0a = ldnt(p0 + rn);     n0b = ldnt(p0 + rn + 4);
        n1a = ldnt(p1 + rn);     n1b = ldnt(p1 + rn + 4);
    }

    float s = 0.f;
#pragma unroll
    for (int i = 0; i < RPT; ++i) {
        const int h  = h0 + i;
        const int hm = (h + 2 < HH) ? h + 2 : HH - 1;     // prefetch row, clamped
        const int rm = hm * WW;
        const vf4 m0a = ldnt(p0 + rm);
        const vf4 m0b = ldnt(p0 + rm + 4);
        const vf4 m1a = ldnt(p1 + rm);
        const vf4 m1b = ldnt(p1 + rm + 4);

        // W-halos from neighbors' center-row registers; image edges clamp.
        float L0 = __shfl_up(c0b.w, 1, 64);   if (lane == 0)  L0 = c0a.x;
        float R0 = __shfl_down(c0a.x, 1, 64); if (lane == 63) R0 = c0b.w;
        float L1 = __shfl_up(c1b.w, 1, 64);   if (lane == 0)  L1 = c1a.x;
        float R1 = __shfl_down(c1a.x, 1, 64); if (lane == 63) R1 = c1b.w;

        const float a0[10] = {L0, c0a.x, c0a.y, c0a.z, c0a.w,
                                  c0b.x, c0b.y, c0b.z, c0b.w, R0};
        const float a1[10] = {L1, c1a.x, c1a.y, c1a.z, c1a.w,
                                  c1b.x, c1b.y, c1b.z, c1b.w, R1};
        const float gx0[8] = {n0a.x - u0a.x, n0a.y - u0a.y, n0a.z - u0a.z, n0a.w - u0a.w,
                              n0b.x - u0b.x, n0b.y - u0b.y, n0b.z - u0b.z, n0b.w - u0b.w};
        const float gx1[8] = {n1a.x - u1a.x, n1a.y - u1a.y, n1a.z - u1a.z, n1a.w - u1a.w,
                              n1b.x - u1b.x, n1b.y - u1b.y, n1b.z - u1b.z, n1b.w - u1b.w};
#pragma unroll
        for (int j = 0; j < 8; ++j) {
            const float gy0 = a0[j + 2] - a0[j];
            const float gy1 = a1[j + 2] - a1[j];
            const float q0  = gx0[j] * gx0[j] + gy0 * gy0 + NGF_EPS;
            const float q1  = gx1[j] * gx1[j] + gy1 * gy1 + NGF_EPS;
            const float cr  = gx0[j] * gx1[j] + gy0 * gy1;
            s += cr * cr * rcp_fast(q0 * q1);   // dot^2 = cross^2/(n0*n1)
        }
        // rotate window (pure register renaming under full unroll)
        u0a = c0a; u0b = c0b; u1a = c1a; u1b = c1b;
        c0a = n0a; c0b = n0b; c1a = n1a; c1b = n1b;
        n0a = m0a; n0b = m0b; n1a = m1a; n1b = m1b;
    }

    // wave64 reduce; lane 0 writes this wave's partial directly (no LDS).
#pragma unroll
    for (int off = 32; off > 0; off >>= 1) s += __shfl_down(s, off, 64);
    if (lane == 0) partials[gw] = s;
}

// 4096 partials: 1024 threads x vf4, one block.
__global__ __launch_bounds__(1024) void ngf_finalize(const float* __restrict__ partials,
                                                     float inv_n,
                                                     float* __restrict__ out) {
    const vf4 v = *(const vf4*)(partials + threadIdx.x * 4);
    float s = v.x + v.y + v.z + v.w;
#pragma unroll
    for (int off = 32; off > 0; off >>= 1) s += __shfl_down(s, off, 64);

    __shared__ float lds[16];
    const int wave = threadIdx.x >> 6;
    const int lane = threadIdx.x & 63;
    if (lane == 0) lds[wave] = s;
    __syncthreads();
    if (threadIdx.x == 0) {
        float tot = 0.f;
#pragma unroll
        for (int i = 0; i < 16; ++i) tot += lds[i];
        out[0] = 1.0f - tot * inv_n;
    }
}

extern "C" void kernel_launch(void* const* d_in, const int* in_sizes, int n_in,
                              void* d_out, int out_size, void* d_ws, size_t ws_size,
                              hipStream_t stream) {
    const float* I0 = (const float*)d_in[0];
    const float* I1 = (const float*)d_in[1];
    float* partials = (float*)d_ws;          // 4096 floats = 16 KB

    const int N = in_sizes[0];               // 16,777,216
    ngf_partial<<<1024, 256, 0, stream>>>(I0, I1, partials);
    ngf_finalize<<<1, 1024, 0, stream>>>(partials, 1.0f / (float)N, (float*)d_out);
}

// Round 7
// 141.011 us; speedup vs baseline: 1.0312x; 1.0312x over previous
//
#include <hip/hip_runtime.h>

// NGF loss: g = normalized gradient (central diff interior, one-sided at edges),
// loss = 1 - mean( (g0 . g1)^2 ).  B=64, C=1, H=512, W=512, fp32.
//
// R16 = champion restore (R14/R9/R0 verbatim). The load-flavor x concurrency
// matrix is now complete:
//            4 w/CU      8 w/CU        16 w/CU
//   plain    46-52(R12)  45-52(R13)    46-49(R11)
//   NT       -           ~40(R0/R14)   ~40-45 no gain (R15)
// Time is decoupled from HBM bytes (FETCH 67-134MB all land 40-52us); the only
// lever that moved time is NT-vs-plain (L1-allocate serializes the miss
// stream; nontemporal bypasses it). Underneath sits a per-CU outstanding-line
// pool: 3.6TB/s / 256CU x ~375ns ~= 82 lines in flight/CU, saturated at >=4
// waves/CU for plain and >=8 for NT (R15: 16 NT waves = no gain). Kernel floor
// = 144MB / ~3.6TB/s ~= 40us = where this sits. Byte-side floor (128MB) is
// unreachable: L1 retention requires plain loads, which cost more than the
// bytes save (R13: -50% FETCH, +12% time). Remaining dur_us is harness fills
// (256MiB @ 6.6TB/s, the entire top-5).

#define HH 512
#define WW 512
#define NGF_EPS 1e-10f
#define RPT 16   // rows walked per wave

typedef float vf4 __attribute__((ext_vector_type(4)));

__device__ __forceinline__ float rcp_fast(float x) { return __builtin_amdgcn_rcpf(x); }
__device__ __forceinline__ vf4 ldnt(const float* p) {
    return __builtin_nontemporal_load((const vf4*)p);
}

// waves = 64 imgs * (512/RPT = 32 chunks) = 2048 -> 512 blocks x 256 threads
__global__ __launch_bounds__(256) void ngf_partial(const float* __restrict__ I0,
                                                   const float* __restrict__ I1,
                                                   float* __restrict__ partials) {
    const int tid  = threadIdx.x;
    const int wv   = tid >> 6;
    const int lane = tid & 63;
    const int gw   = blockIdx.x * 4 + wv;   // global wave id, 0..2047
    const int img  = gw >> 5;               // 0..63
    const int ck   = gw & 31;               // row-chunk 0..31
    const int h0   = ck * RPT;

    const float* p0 = I0 + (size_t)img * (HH * WW) + lane * 8;
    const float* p1 = I1 + (size_t)img * (HH * WW) + lane * 8;

    // 3-row window (u = h-1 clamped, c = h, n = h+1) + prefetch m = h+2.
    vf4 u0a, u0b, u1a, u1b, c0a, c0b, c1a, c1b, n0a, n0b, n1a, n1b;
    {
        const int ru = (h0 > 0) ? (h0 - 1) * WW : 0;
        const int rc = h0 * WW;
        const int rn = (h0 + 1) * WW;       // h0 <= 496 -> always valid
        u0a = ldnt(p0 + ru);     u0b = ldnt(p0 + ru + 4);
        u1a = ldnt(p1 + ru);     u1b = ldnt(p1 + ru + 4);
        c0a = ldnt(p0 + rc);     c0b = ldnt(p0 + rc + 4);
        c1a = ldnt(p1 + rc);     c1b = ldnt(p1 + rc + 4);
        n0a = ldnt(p0 + rn);     n0b = ldnt(p0 + rn + 4);
        n1a = ldnt(p1 + rn);     n1b = ldnt(p1 + rn + 4);
    }

    float s = 0.f;
#pragma unroll
    for (int i = 0; i < RPT; ++i) {
        const int h  = h0 + i;
        const int hm = (h + 2 < HH) ? h + 2 : HH - 1;     // prefetch row, clamped
        const int rm = hm * WW;
        const vf4 m0a = ldnt(p0 + rm);
        const vf4 m0b = ldnt(p0 + rm + 4);
        const vf4 m1a = ldnt(p1 + rm);
        const vf4 m1b = ldnt(p1 + rm + 4);

        // W-halos from neighbors' center-row registers; image edges clamp.
        float L0 = __shfl_up(c0b.w, 1, 64);   if (lane == 0)  L0 = c0a.x;
        float R0 = __shfl_down(c0a.x, 1, 64); if (lane == 63) R0 = c0b.w;
        float L1 = __shfl_up(c1b.w, 1, 64);   if (lane == 0)  L1 = c1a.x;
        float R1 = __shfl_down(c1a.x, 1, 64); if (lane == 63) R1 = c1b.w;

        const float a0[10] = {L0, c0a.x, c0a.y, c0a.z, c0a.w,
                                  c0b.x, c0b.y, c0b.z, c0b.w, R0};
        const float a1[10] = {L1, c1a.x, c1a.y, c1a.z, c1a.w,
                                  c1b.x, c1b.y, c1b.z, c1b.w, R1};
        const float gx0[8] = {n0a.x - u0a.x, n0a.y - u0a.y, n0a.z - u0a.z, n0a.w - u0a.w,
                              n0b.x - u0b.x, n0b.y - u0b.y, n0b.z - u0b.z, n0b.w - u0b.w};
        const float gx1[8] = {n1a.x - u1a.x, n1a.y - u1a.y, n1a.z - u1a.z, n1a.w - u1a.w,
                              n1b.x - u1b.x, n1b.y - u1b.y, n1b.z - u1b.z, n1b.w - u1b.w};
#pragma unroll
        for (int j = 0; j < 8; ++j) {
            const float gy0 = a0[j + 2] - a0[j];
            const float gy1 = a1[j + 2] - a1[j];
            const float q0  = gx0[j] * gx0[j] + gy0 * gy0 + NGF_EPS;
            const float q1  = gx1[j] * gx1[j] + gy1 * gy1 + NGF_EPS;
            const float cr  = gx0[j] * gx1[j] + gy0 * gy1;
            s += cr * cr * rcp_fast(q0 * q1);   // dot^2 = cross^2/(n0*n1)
        }
        // rotate window (pure register renaming under full unroll)
        u0a = c0a; u0b = c0b; u1a = c1a; u1b = c1b;
        c0a = n0a; c0b = n0b; c1a = n1a; c1b = n1b;
        n0a = m0a; n0b = m0b; n1a = m1a; n1b = m1b;
    }

    // wave64 reduce; lane 0 writes this wave's partial directly (no LDS).
#pragma unroll
    for (int off = 32; off > 0; off >>= 1) s += __shfl_down(s, off, 64);
    if (lane == 0) partials[gw] = s;
}

// 2048 partials: 512 threads x vf4, one block.
__global__ __launch_bounds__(512) void ngf_finalize(const float* __restrict__ partials,
                                                    float inv_n,
                                                    float* __restrict__ out) {
    const vf4 v = *(const vf4*)(partials + threadIdx.x * 4);
    float s = v.x + v.y + v.z + v.w;
#pragma unroll
    for (int off = 32; off > 0; off >>= 1) s += __shfl_down(s, off, 64);

    __shared__ float lds[8];
    const int wave = threadIdx.x >> 6;
    const int lane = threadIdx.x & 63;
    if (lane == 0) lds[wave] = s;
    __syncthreads();
    if (threadIdx.x == 0) {
        float tot = 0.f;
#pragma unroll
        for (int i = 0; i < 8; ++i) tot += lds[i];
        out[0] = 1.0f - tot * inv_n;
    }
}

extern "C" void kernel_launch(void* const* d_in, const int* in_sizes, int n_in,
                              void* d_out, int out_size, void* d_ws, size_t ws_size,
                              hipStream_t stream) {
    const float* I0 = (const float*)d_in[0];
    const float* I1 = (const float*)d_in[1];
    float* partials = (float*)d_ws;          // 2048 floats = 8 KB

    const int N = in_sizes[0];               // 16,777,216
    ngf_partial<<<512, 256, 0, stream>>>(I0, I1, partials);
    ngf_finalize<<<1, 512, 0, stream>>>(partials, 1.0f / (float)N, (float*)d_out);
}